// Round 10
// baseline (512.210 us; speedup 1.0000x reference)
//
#include <hip/hip_runtime.h>

#define CCH   640
#define RDIM  128
#define NBS   25
#define NBQ   75
#define CKK   5760
#define SF_B  64000
#define NBLK  256
#define NTHR  512

// ---------------- Workspace layout (float offsets) ----------------
// ws[0..63]: int barrier cells (zeroed by 256B memset each call)
#define OFF_PG0 64       // [25][640]
#define OFF_PGA 16064
#define OFF_PGB 32064
#define OFF_AA  48064    // [9][640]
#define OFF_AB  53824
#define OFF_BBA 59584    // [16]
#define OFF_BBB 59600
#define OFF_HC  59616    // [50][128] (0-24 task, 25-49 support)
#define OFF_SKT 66016    // [25][900] layout [b][uv*100+p]   (atomic, intra-kernel)
#define OFF_SKS 88516    // [9][25][100]                     (normal, invol-only)
#define OFF_CKS 111016   // [25][5760]                       (normal, invol-only)
#define OFF_TKT 255016   // [9][640][100]                    (normal, invol-only)

__device__ __forceinline__ float aload(const float* p) {
    return __hip_atomic_load((float*)p, __ATOMIC_RELAXED, __HIP_MEMORY_SCOPE_AGENT);
}
__device__ __forceinline__ void astore(float* p, float v) {
    __hip_atomic_store(p, v, __ATOMIC_RELAXED, __HIP_MEMORY_SCOPE_AGENT);
}

// Fence-free global barrier: __syncthreads drains vmem (compiler emits vmcnt(0)
// before s_barrier); arrive+poll are agent-scope atomics at the coherence point.
// NO __threadfence => caches stay warm (the R7/R8 killer removed).
__device__ __forceinline__ void gbar(int* cnt, int id) {
    __syncthreads();
    if (threadIdx.x == 0) {
        asm volatile("s_waitcnt vmcnt(0)" ::: "memory");
        __hip_atomic_fetch_add(&cnt[id], 1, __ATOMIC_RELAXED, __HIP_MEMORY_SCOPE_AGENT);
        while (__hip_atomic_load(&cnt[id], __ATOMIC_RELAXED, __HIP_MEMORY_SCOPE_AGENT) < NBLK)
            __builtin_amdgcn_s_sleep(8);
    }
    __syncthreads();
}

__global__ __launch_bounds__(NTHR) void uber(
        const float* __restrict__ sf,
        const float* __restrict__ Wc0, const float* __restrict__ bc0,
        const float* __restrict__ Wc1, const float* __restrict__ bc1,
        const float* __restrict__ Wc2, const float* __restrict__ bc2,
        const float* __restrict__ Wc3, const float* __restrict__ bc3,
        const float* __restrict__ W1,  const float* __restrict__ b1,
        const float* __restrict__ W2,  const float* __restrict__ b2,
        const float* __restrict__ Ws,  const float* __restrict__ bs,
        float* ws) {
    __shared__ float smem[9600];      // 38.4 KB union, 1 block/CU resident
    int* bar = (int*)ws;
    float* PG0 = ws + OFF_PG0;
    float* PGA = ws + OFF_PGA;
    float* PGB = ws + OFF_PGB;
    float* AA  = ws + OFF_AA;
    float* AB  = ws + OFF_AB;
    float* BBA = ws + OFF_BBA;
    float* BBB = ws + OFF_BBB;
    float* HC  = ws + OFF_HC;
    float* SKT = ws + OFF_SKT;
    float* SKS = ws + OFF_SKS;
    float* CKS = ws + OFF_CKS;
    float* TKT = ws + OFF_TKT;

    int blk = blockIdx.x, t = threadIdx.x;
    int wv = t >> 6, lane = t & 63;

    // ---- P0: pool (blocks 0..31, atomic out) + skS (32..76, normal out) ----
    if (blk < 32) {
        int idx = blk * NTHR + t;
        if (idx < NBS * CCH) {
            int b = idx / CCH, c = idx % CCH;
            const float4* s4 = (const float4*)(sf + b * SF_B + c * 100);
            float acc = 0.f;
#pragma unroll
            for (int q = 0; q < 25; ++q) {
                float4 v = s4[q];
                acc += (v.x + v.y) + (v.z + v.w);
            }
            astore(&PG0[idx], acc * 0.01f);
        }
    } else if (blk < 77) {
        int idx = (blk - 32) * NTHR + t;
        if (idx < NBS * 900) {
            int b = idx / 900, r2 = idx % 900;    // flat f = k*100+q
            int k = r2 / 100, q = r2 % 100;
            const float* x = sf + b * SF_B + q;
            const float* wsr = Ws + k * CCH;
            float acc = bs[k];
#pragma unroll 8
            for (int c = 0; c < CCH; ++c)
                acc += wsr[c] * x[c * 100];
            int p = r2 / 9, uv = r2 % 9;
            SKS[uv * 2500 + b * 100 + p] = acc;   // normal: invol-only consumer
        }
    }
    gbar(bar, 0);

    // ---- P1..P4: chain steps ----
    {
        const float* Wcf[4] = {Wc0, Wc1, Wc2, Wc3};
        const float* bcf[4] = {bc0, bc1, bc2, bc3};
        const float* Pin_[4] = {PG0, PGA, PGB, PGA};
        float*       Pout_[4] = {PGA, PGB, PGA, PGB};
        const float* Ain_[4] = {Ws, AA, AB, AA};
        float*       Aout_[4] = {AA, AB, AA, AB};
        const float* Bin_[4] = {bs, BBA, BBB, BBA};
        float*       Bout_[4] = {BBA, BBB, BBA, BBB};
        float* red = smem;             // [512]
        float* stg = smem + 512;       // [640]
        for (int s = 0; s < 4; ++s) {
            int first = (s == 0);
            const float* Wa = Wcf[3 - s];
            const float* ba = bcf[3 - s];
            if (blk < 90) {
                // A'[k,c] = sum_o A[k,o]*Wa[o,c]
                int k = blk / 10, ctile = blk % 10;
                for (int i = t; i < CCH; i += NTHR)
                    stg[i] = first ? Ws[k * CCH + i] : aload(Ain_[s] + k * CCH + i);
                __syncthreads();
                int c = ctile * 64 + lane;
                int o0 = wv * 80;
                float acc = 0.f;
#pragma unroll 8
                for (int o = o0; o < o0 + 80; ++o)
                    acc += stg[o] * Wa[o * CCH + c];
                red[t] = acc;
                __syncthreads();
                if (t < 64) {
                    float sa = 0.f;
#pragma unroll
                    for (int g = 0; g < 8; ++g) sa += red[g * 64 + t];
                    astore(&Aout_[s][k * CCH + ctile * 64 + t], sa);
                }
            } else if (blk < 99) {
                // beta' = beta + A[k,:].ba
                int k = blk - 90;
                for (int i = t; i < CCH; i += NTHR)
                    stg[i] = first ? Ws[k * CCH + i] : aload(Ain_[s] + k * CCH + i);
                __syncthreads();
                float v = stg[t] * ba[t];
                if (t < CCH - NTHR) v += stg[t + NTHR] * ba[t + NTHR];
                red[t] = v;
                __syncthreads();
                if (t < 64) {
                    float sa = 0.f;
#pragma unroll
                    for (int g = 0; g < 8; ++g) sa += red[g * 64 + t];
#pragma unroll
                    for (int m = 32; m >= 1; m >>= 1) sa += __shfl_xor(sa, m);
                    if (t == 0)
                        astore(&Bout_[s][k], sa + (first ? bs[k] : aload(Bin_[s] + k)));
                }
            } else if (blk < 124) {
                // P'[b,o] = Wp[o,:].P[b,:] + bp[o]  (block per b, wave per o)
                int b = blk - 99;
                for (int i = t; i < CCH; i += NTHR)
                    stg[i] = aload(Pin_[s] + b * CCH + i);
                __syncthreads();
                const float* Wp = Wcf[s];
                const float* bp = bcf[s];
                for (int g = 0; g < 80; ++g) {
                    int o = wv * 80 + g;
                    const float* wrow = Wp + o * CCH;
                    float acc = 0.f;
#pragma unroll
                    for (int s5 = 0; s5 < 10; ++s5)
                        acc += wrow[s5 * 64 + lane] * stg[s5 * 64 + lane];
#pragma unroll
                    for (int m = 32; m >= 1; m >>= 1) acc += __shfl_xor(acc, m);
                    if (lane == 0) astore(&Pout_[s][b * CCH + o], acc + bp[o]);
                }
            }
            gbar(bar, 1 + s);
        }
    }
    // pooled_task = PGB, A4 = AB, beta4 = BBB

    // ---- P5: mlp1 (blocks 0..49) + skT (50..94, atomic out) ----
    if (blk < 50) {
        float* red = smem;
        float* stg = smem + 512;
        int pair = blk;
        int b = pair % NBS;
        const float* src = (pair < NBS ? PGB : PG0) + b * CCH;
        for (int i = t; i < CCH; i += NTHR) stg[i] = aload(src + i);
        __syncthreads();
        int og = t >> 7, r = t & 127;
        int c0 = og * 160;
        float acc = 0.f;
#pragma unroll 8
        for (int c = c0; c < c0 + 160; ++c)
            acc += stg[c] * W1[c * RDIM + r];
        red[t] = acc;
        __syncthreads();
        if (t < RDIM) {
            float h = b1[t] + red[t] + red[RDIM + t] + red[2 * RDIM + t] + red[3 * RDIM + t];
            astore(&HC[pair * RDIM + t], fmaxf(h, 0.f));
        }
    } else if (blk < 95) {
        float* sA4 = smem;             // [5760]
        float* sBt = smem + 5760;      // [9]
        for (int i = t; i < 9 * CCH; i += NTHR) sA4[i] = aload(AB + i);
        if (t < 9) sBt[t] = aload(BBB + t);
        __syncthreads();
        int idx = (blk - 50) * NTHR + t;
        if (idx < NBS * 900) {
            int b = idx / 900, r2 = idx % 900;
            int k = r2 / 100, q = r2 % 100;
            const float* x = sf + b * SF_B + q;
            const float* a4r = sA4 + k * CCH;
            float acc = sBt[k];
#pragma unroll 8
            for (int c = 0; c < CCH; ++c)
                acc += a4r[c] * x[c * 100];
            int p = r2 / 9, uv = r2 % 9;
            astore(&SKT[b * 900 + uv * 100 + p], acc);
        }
    }
    gbar(bar, 5);

    // ---- P6: fused task (grid-strided tiles) + CKS; outputs normal ----
    {
        float* sHT = smem;             // [6400]
        float* sW2 = smem + 6400;      // [512]
        float* sSK = smem + 6912;      // [2500]
        float* sCK = smem + 9412;      // [100]
        for (int i = t; i < 50 * RDIM; i += NTHR) sHT[i] = aload(HC + i);
        for (int tile = blk; tile < 1440; tile += NBLK) {
            __syncthreads();
            int uv = tile / 160, cg = tile % 160;
            int c0 = cg * 4;
            {
                int ci = t >> 7, r = t & 127;
                sW2[ci * RDIM + r] = W2[r * CKK + (c0 + ci) * 9 + uv];
            }
            for (int i = t; i < 2500; i += NTHR) {
                int b = i / 100, p = i % 100;
                sSK[i] = aload(&SKT[b * 900 + uv * 100 + p]);
            }
            __syncthreads();
            if (t < 100) {
                int ci = t / 25, b = t % 25;
                const float* h = sHT + b * RDIM;
                const float* w = sW2 + ci * RDIM;
                float acc = b2[(c0 + ci) * 9 + uv];
#pragma unroll 8
                for (int r = 0; r < RDIM; ++r) acc += h[r] * w[r];
                sCK[ci * 25 + b] = acc;
            }
            __syncthreads();
            if (t < 400) {
                int ci = t / 100, p = t % 100;
                float acc = 0.f;
#pragma unroll
                for (int b = 0; b < NBS; ++b)
                    acc += sCK[ci * 25 + b] * sSK[b * 100 + p];
                TKT[uv * 64000 + (c0 + ci) * 100 + p] = acc * 0.04f;  // normal
            }
        }
        // CKS = h_s @ W2 + b2
        for (int job = blk * NTHR + t; job < NBS * CKK; job += NBLK * NTHR) {
            int b = job / CKK, j = job % CKK;
            const float* h = sHT + (NBS + b) * RDIM;
            float acc = b2[j];
#pragma unroll 8
            for (int r = 0; r < RDIM; ++r)
                acc += h[r] * W2[r * CKK + j];
            CKS[b * CKK + j] = acc;                                   // normal
        }
    }
}

// Dispatch 2: involutions (kernel boundary gives coherence; all normal loads)
__global__ __launch_bounds__(NTHR) void k_invol(
        const float* __restrict__ sf, const float* __restrict__ qf,
        const float* __restrict__ TKT, const float* __restrict__ CKS,
        const float* __restrict__ SKS, float* __restrict__ out) {
    int oidx = blockIdx.x * NTHR + threadIdx.x;      // exactly 6.4M
    bool support = oidx < NBS * SF_B;
    int b, c, p;
    const float* x;
    if (support) {
        b = oidx / SF_B; int rem = oidx % SF_B; c = rem / 100; p = rem % 100;
        x = sf + b * SF_B + c * 100;
    } else {
        int qi = oidx - NBS * SF_B;
        b = qi / SF_B; int rem = qi % SF_B; c = rem / 100; p = rem % 100;
        x = qf + b * SF_B + c * 100;
    }
    int i = p / 10, j = p % 10;
    float acc = 0.f;
#pragma unroll
    for (int u = 0; u < 3; ++u) {
        int ii = i + u - 1;
        float mrow = ((unsigned)ii < 10u) ? 1.f : 0.f;
        int ci = min(max(ii, 0), 9);
#pragma unroll
        for (int v = 0; v < 3; ++v) {
            int jj = j + v - 1;
            float m = ((unsigned)jj < 10u) ? mrow : 0.f;
            int cj = min(max(jj, 0), 9);
            float xv = x[ci * 10 + cj] * m;
            int uv = u * 3 + v;
            float w = TKT[uv * 64000 + c * 100 + p];
            if (support)
                w *= CKS[b * CKK + c * 9 + uv] * SKS[uv * 2500 + b * 100 + p];
            acc += w * xv;
        }
    }
    out[oidx] = acc;
}

extern "C" void kernel_launch(void* const* d_in, const int* in_sizes, int n_in,
                              void* d_out, int out_size, void* d_ws, size_t ws_size,
                              hipStream_t stream) {
    const float* sf  = (const float*)d_in[0];
    const float* qf  = (const float*)d_in[1];
    const float* Wc0 = (const float*)d_in[2];
    const float* bc0 = (const float*)d_in[3];
    const float* Wc1 = (const float*)d_in[4];
    const float* bc1 = (const float*)d_in[5];
    const float* Wc2 = (const float*)d_in[6];
    const float* bc2 = (const float*)d_in[7];
    const float* Wc3 = (const float*)d_in[8];
    const float* bc3 = (const float*)d_in[9];
    const float* W1 = (const float*)d_in[10];
    const float* b1 = (const float*)d_in[11];
    const float* W2 = (const float*)d_in[12];
    const float* b2 = (const float*)d_in[13];
    const float* Ws = (const float*)d_in[14];
    const float* bs = (const float*)d_in[15];
    float* out = (float*)d_out;
    float* ws = (float*)d_ws;

    hipMemsetAsync(d_ws, 0, 64 * sizeof(int), stream);   // barrier cells
    uber<<<NBLK, NTHR, 0, stream>>>(sf, Wc0, bc0, Wc1, bc1, Wc2, bc2, Wc3, bc3,
                                    W1, b1, W2, b2, Ws, bs, ws);
    k_invol<<<12500, NTHR, 0, stream>>>(sf, qf, ws + OFF_TKT, ws + OFF_CKS,
                                        ws + OFF_SKS, out);
}